// Round 2
// baseline (407.398 us; speedup 1.0000x reference)
//
#include <hip/hip_runtime.h>
#include <cstddef>

#define NC 64

__global__ __launch_bounds__(64)
void crf_nll_kernel(const float* __restrict__ logits,
                    const float* __restrict__ trans,
                    const float* __restrict__ init_alphas,
                    const int*  __restrict__ lengths,
                    const int*  __restrict__ tags,
                    float* __restrict__ out,
                    int N, int T)
{
    const int n = blockIdx.x;
    const int lane = threadIdx.x;          // 0..63, owns class row `lane`
    const float* lg = logits + (size_t)n * T * NC;
    const int len = lengths[n];            // in [2, T]
    const int Tm1 = T - 1;

    __shared__ __align__(16) float v_lds[NC];

    // E row for this lane: exp(trans[lane][j]) -> 64 VGPRs
    float E[NC];
    #pragma unroll
    for (int j = 0; j < NC; ++j)
        E[j] = __expf(trans[lane * NC + j]);

    // alpha_0 = init + logits[0]; switch to linear domain v = exp(alpha - L)
    float a0 = init_alphas[lane] + lg[lane];
    float L  = __int_as_float(__builtin_amdgcn_readfirstlane(__float_as_int(a0)));
    float v  = __expf(a0 - L);

    // software pipeline: f = exp(logit row t) ready for current step;
    // r1,r2,r3 = raw rows t+1, t+2, t+3 (r3 just issued)
    float f  = __expf(lg[NC * 1 + lane]);                      // row 1 (len>=2)
    float r1 = lg[NC * (2 < Tm1 ? 2 : Tm1) + lane];
    float r2 = lg[NC * (3 < Tm1 ? 3 : Tm1) + lane];
    float r3 = lg[NC * (4 < Tm1 ? 4 : Tm1) + lane];

    for (int t = 1; t < len; ++t) {
        v_lds[lane] = v;                   // single wave: in-order DS, no barrier

        int prow = t + 4; prow = prow < Tm1 ? prow : Tm1;      // clamp, off-chain
        float rnew = lg[NC * prow + lane]; // issue prefetch (3 iters of slack)
        float fn = __expf(r1);             // exp for NEXT step, off current chain

        const float4* p4 = reinterpret_cast<const float4*>(v_lds);
        float s0 = 0.f, s1 = 0.f, s2 = 0.f, s3 = 0.f;
        #pragma unroll
        for (int jj = 0; jj < 16; ++jj) {
            const float4 pv = p4[jj];      // broadcast reads, conflict-free
            s0 = __fmaf_rn(E[4*jj+0], pv.x, s0);
            s1 = __fmaf_rn(E[4*jj+1], pv.y, s1);
            s2 = __fmaf_rn(E[4*jj+2], pv.z, s2);
            s3 = __fmaf_rn(E[4*jj+3], pv.w, s3);
        }
        const float dot = (s0 + s1) + (s2 + s3);
        v = f * dot;                       // linear-domain update

        if ((t & 7) == 0) {
            // exact power-of-2 rescale: strip lane-0's exponent
            unsigned bits = (unsigned)__builtin_amdgcn_readfirstlane((int)__float_as_uint(v));
            int e = (int)((bits >> 23) & 0xFF);                // biased exponent
            v *= __uint_as_float((unsigned)(254 - e) << 23);   // *= 2^(127-e)
            L += (float)(e - 127) * 0.6931471805599453f;
        }
        f = fn; r1 = r2; r2 = r3; r3 = rnew;
    }

    // logZ = L + log(sum_i v_i)
    float p2 = v;
    #pragma unroll
    for (int off = 32; off; off >>= 1) p2 += __shfl_xor(p2, off);
    const float logZ = L + __logf(p2);

    // gold score: first + sum_{t>=1} trans[tag_t, tag_{t-1}] + logit[t, tag_t]
    const int* tg = tags + (size_t)n * T;
    float g = 0.f;
    for (int t = 1 + lane; t < len; t += 64) {
        const int cur = tg[t];
        const int prv = tg[t - 1];
        g += trans[cur * NC + prv] + lg[t * NC + cur];
    }
    #pragma unroll
    for (int off = 32; off; off >>= 1) g += __shfl_xor(g, off);

    if (lane == 0) {
        const int t0 = tg[0];
        const float gold = init_alphas[t0] + lg[t0] + g;
        out[n] = logZ - gold;
    }
}

extern "C" void kernel_launch(void* const* d_in, const int* in_sizes, int n_in,
                              void* d_out, int out_size, void* d_ws, size_t ws_size,
                              hipStream_t stream)
{
    const float* logits = (const float*)d_in[0];   // [N][T][C] f32
    const float* trans  = (const float*)d_in[1];   // [C][C]    f32
    const float* inita  = (const float*)d_in[2];   // [C]       f32
    const int*   lens   = (const int*)d_in[3];     // [N]       i32
    const int*   tags   = (const int*)d_in[4];     // [N][T]    i32
    float*       out    = (float*)d_out;           // [N]       f32

    const int N = 512, T = 1024;
    crf_nll_kernel<<<N, 64, 0, stream>>>(logits, trans, inita, lens, tags, out, N, T);
}